// Round 1
// baseline (209.463 us; speedup 1.0000x reference)
//
#include <hip/hip_runtime.h>
#include <math.h>

#define BB 16
#define NN 4096
#define KK 32
#define NF 12

__device__ __forceinline__ float4 ldf4(const float* p) { return *(const float4*)p; }

// Kernel 1: h = relu(x @ We + be)  [B,N,12] into ws; also transpose the 6
// weight matrices [24,12] -> [12,24] (f-major) so the branch kernel reads
// 24 contiguous floats per output feature via scalar loads.
__global__ __launch_bounds__(256) void prep_kernel(
    const float* __restrict__ x,
    const float* __restrict__ We, const float* __restrict__ be,
    const float* __restrict__ Wm1, const float* __restrict__ Wu1,
    const float* __restrict__ Wm0, const float* __restrict__ Wu0,
    const float* __restrict__ Wmm1, const float* __restrict__ Wum1,
    float* __restrict__ h, float* __restrict__ wT)
{
    int node = blockIdx.x * 256 + threadIdx.x;
    float4 xv = ((const float4*)x)[node];
    float hv[NF];
#pragma unroll
    for (int f = 0; f < NF; f++) {
        float s = be[f];
        s = fmaf(xv.x, We[0 * NF + f], s);
        s = fmaf(xv.y, We[1 * NF + f], s);
        s = fmaf(xv.z, We[2 * NF + f], s);
        s = fmaf(xv.w, We[3 * NF + f], s);
        hv[f] = fmaxf(s, 0.0f);
    }
    float4* hp = (float4*)(h + (size_t)node * NF);
    hp[0] = make_float4(hv[0], hv[1], hv[2], hv[3]);
    hp[1] = make_float4(hv[4], hv[5], hv[6], hv[7]);
    hp[2] = make_float4(hv[8], hv[9], hv[10], hv[11]);

    if (blockIdx.x == 0) {
        int t = threadIdx.x;
        // layout: branch-major: [Wm1T, Wu1T, Wm0T, Wu0T, Wmm1T, Wum1T], 288 floats each
#pragma unroll
        for (int mtx = 0; mtx < 6; mtx++) {
            const float* Wsrc = (mtx == 0) ? Wm1 : (mtx == 1) ? Wu1 :
                                (mtx == 2) ? Wm0 : (mtx == 3) ? Wu0 :
                                (mtx == 4) ? Wmm1 : Wum1;
            for (int e = t; e < 288; e += 256) {
                int f = e / 24, j = e % 24;
                wT[mtx * 288 + e] = Wsrc[j * NF + f];
            }
        }
    }
}

// Kernel 2: one thread per (branch,b,n) node. K-tile = 4 neighbors resident
// in registers; weight columns fetched per output feature via uniform
// (scalar-cache) loads, amortized over the 4 neighbors.
__global__ __launch_bounds__(256) void branch_kernel(
    const float* __restrict__ h,
    const float* __restrict__ d1, const float* __restrict__ d0, const float* __restrict__ dm1,
    const float* __restrict__ wT,
    const float* __restrict__ bm1, const float* __restrict__ bu1,
    const float* __restrict__ bm0, const float* __restrict__ bu0,
    const float* __restrict__ bmm1, const float* __restrict__ bum1,
    float* __restrict__ out)
{
    const int br = blockIdx.z;
    const int b  = blockIdx.y;
    const int n  = blockIdx.x * 256 + threadIdx.x;

    const float* dptr = (br == 0) ? d1 : (br == 1) ? d0 : dm1;
    const float* bm   = (br == 0) ? bm1 : (br == 1) ? bm0 : bmm1;
    const float* bu   = (br == 0) ? bu1 : (br == 1) ? bu0 : bum1;
    const float* wmT  = wT + br * 576;        // [12][24] message weights^T
    const float* wuT  = wmT + 288;            // [12][24] update weights^T

    const float* hB = h + (size_t)b * NN * NF;
    const float* hn = hB + (size_t)n * NF;
    float hv[NF];
    {
        float4 a = ldf4(hn), c = ldf4(hn + 4), e = ldf4(hn + 8);
        hv[0] = a.x; hv[1] = a.y; hv[2]  = a.z; hv[3]  = a.w;
        hv[4] = c.x; hv[5] = c.y; hv[6]  = c.z; hv[7]  = c.w;
        hv[8] = e.x; hv[9] = e.y; hv[10] = e.z; hv[11] = e.w;
    }
    float m[NF];
#pragma unroll
    for (int f = 0; f < NF; f++) m[f] = 0.0f;

    const float* dp = dptr + ((size_t)(b * NN + n)) * KK * 2;
    const float Cexp = -2222.2222222222f;     // -1/(2*sigma^2), sigma=0.015

#pragma unroll 1
    for (int kt = 0; kt < KK / 4; kt++) {
        float4 dv0 = ldf4(dp + kt * 8);
        float4 dv1 = ldf4(dp + kt * 8 + 4);
        int   idx[4]  = { (int)dv0.x, (int)dv0.z, (int)dv1.x, (int)dv1.z };
        float dist[4] = { dv0.y, dv0.w, dv1.y, dv1.w };

        float hj[4][NF], rb[4][NF];
#pragma unroll
        for (int kk = 0; kk < 4; kk++) {
            const float* hjp = hB + (size_t)idx[kk] * NF;
            float4 a = ldf4(hjp), c = ldf4(hjp + 4), e = ldf4(hjp + 8);
            hj[kk][0] = a.x; hj[kk][1] = a.y; hj[kk][2]  = a.z; hj[kk][3]  = a.w;
            hj[kk][4] = c.x; hj[kk][5] = c.y; hj[kk][6]  = c.z; hj[kk][7]  = c.w;
            hj[kk][8] = e.x; hj[kk][9] = e.y; hj[kk][10] = e.z; hj[kk][11] = e.w;
        }
#pragma unroll
        for (int kk = 0; kk < 4; kk++) {
#pragma unroll
            for (int j = 0; j < NF; j++) {
                float t = dist[kk] - (0.3f / 11.0f) * j;
                rb[kk][j] = __expf(Cexp * t * t);
            }
        }
#pragma unroll
        for (int f = 0; f < NF; f++) {
            const float* w = wmT + f * 24;    // uniform address -> scalar loads
            float bmf = bm[f];
#pragma unroll
            for (int kk = 0; kk < 4; kk++) {
                float s = bmf;
#pragma unroll
                for (int j = 0; j < NF; j++) s = fmaf(hj[kk][j], w[j], s);
#pragma unroll
                for (int j = 0; j < NF; j++) s = fmaf(rb[kk][j], w[NF + j], s);
                m[f] += fmaxf(s, 0.0f);
            }
        }
    }

    float o[NF];
#pragma unroll
    for (int f = 0; f < NF; f++) {
        const float* w = wuT + f * 24;
        float a = bu[f];
#pragma unroll
        for (int j = 0; j < NF; j++) a = fmaf(hv[j], w[j], a);
#pragma unroll
        for (int j = 0; j < NF; j++) a = fmaf(m[j], w[NF + j], a);
        o[f] = 1.0f / (1.0f + __expf(-a));
    }
    float* op = out + ((size_t)br * BB * NN + (size_t)b * NN + n) * NF;
    float4* op4 = (float4*)op;
    op4[0] = make_float4(o[0], o[1], o[2],  o[3]);
    op4[1] = make_float4(o[4], o[5], o[6],  o[7]);
    op4[2] = make_float4(o[8], o[9], o[10], o[11]);
}

extern "C" void kernel_launch(void* const* d_in, const int* in_sizes, int n_in,
                              void* d_out, int out_size, void* d_ws, size_t ws_size,
                              hipStream_t stream)
{
    const float* x    = (const float*)d_in[0];
    const float* d1   = (const float*)d_in[1];
    const float* d0   = (const float*)d_in[2];
    const float* dm1  = (const float*)d_in[3];
    // d_in[4] = mask [B,N] bool, all ones in reference semantics -> unused
    const float* We   = (const float*)d_in[5];
    const float* be   = (const float*)d_in[6];
    const float* Wm1  = (const float*)d_in[7];
    const float* bm1  = (const float*)d_in[8];
    const float* Wu1  = (const float*)d_in[9];
    const float* bu1  = (const float*)d_in[10];
    const float* Wm0  = (const float*)d_in[11];
    const float* bm0  = (const float*)d_in[12];
    const float* Wu0  = (const float*)d_in[13];
    const float* bu0  = (const float*)d_in[14];
    const float* Wmm1 = (const float*)d_in[15];
    const float* bmm1 = (const float*)d_in[16];
    const float* Wum1 = (const float*)d_in[17];
    const float* bum1 = (const float*)d_in[18];

    float* h  = (float*)d_ws;                       // [B*N, 12] = 3 MB
    float* wT = h + (size_t)BB * NN * NF;           // 6 * 288 floats

    prep_kernel<<<dim3(BB * NN / 256), 256, 0, stream>>>(
        x, We, be, Wm1, Wu1, Wm0, Wu0, Wmm1, Wum1, h, wT);
    branch_kernel<<<dim3(NN / 256, BB, 3), 256, 0, stream>>>(
        h, d1, d0, dm1, wT, bm1, bu1, bm0, bu0, bmm1, bum1, (float*)d_out);
}

// Round 2
// 148.676 us; speedup vs baseline: 1.4089x; 1.4089x over previous
//
#include <hip/hip_runtime.h>
#include <hip/hip_fp16.h>
#include <math.h>

#define BBAT 16
#define NNODE 4096
#define KNB 32
#define NF 12
#define TBL 512          // lerp table intervals; 513 entries
#define NPB 820          // nodes per main block (5 blocks cover 4096)
#define TMAIN 832        // 13 waves

// LDS layout (dynamic, 110616 B total):
//   gAl: uint4[4096]   @ 0       (g halves 0..7,  per node)
//   gBl: uint2[4096]   @ 65536   (g halves 8..11)
//   tAl: uint4[513]    @ 98304   (phi halves 0..7, per table entry)
//   tBl: uint2[513]    @ 106512  (phi halves 8..11)
#define LDS_BYTES 110616

__device__ __forceinline__ __half2 u2h(unsigned int u) { __half2 h; __builtin_memcpy(&h, &u, 4); return h; }
__device__ __forceinline__ unsigned int h2u(__half2 h) { unsigned int u; __builtin_memcpy(&u, &h, 4); return u; }
__device__ __forceinline__ float4 ldf4(const float* p) { return *(const float4*)p; }

// ---------------------------------------------------------------------------
// prep: h = relu(x@We+be)  (f32, ws) ; g_br = h@Wm_br[0:12] + bm_br (f16 packed)
// ---------------------------------------------------------------------------
__global__ __launch_bounds__(256) void prep_kernel(
    const float* __restrict__ x, const float* __restrict__ We, const float* __restrict__ be,
    const float* __restrict__ Wm1, const float* __restrict__ bm1,
    const float* __restrict__ Wm0, const float* __restrict__ bm0,
    const float* __restrict__ Wmm1, const float* __restrict__ bmm1,
    float* __restrict__ h, uint4* __restrict__ gA, uint2* __restrict__ gB)
{
    const int node = blockIdx.x * 256 + threadIdx.x;   // == b*4096+n, [0,65536)
    float4 xv = ((const float4*)x)[node];
    float hv[NF];
#pragma unroll
    for (int f = 0; f < NF; f++) {
        float s = be[f];
        s = fmaf(xv.x, We[0 * NF + f], s);
        s = fmaf(xv.y, We[1 * NF + f], s);
        s = fmaf(xv.z, We[2 * NF + f], s);
        s = fmaf(xv.w, We[3 * NF + f], s);
        hv[f] = fmaxf(s, 0.0f);
    }
    float4* hp = (float4*)(h + (size_t)node * NF);
    hp[0] = make_float4(hv[0], hv[1], hv[2], hv[3]);
    hp[1] = make_float4(hv[4], hv[5], hv[6], hv[7]);
    hp[2] = make_float4(hv[8], hv[9], hv[10], hv[11]);

#define DO_G(BR, WM, BM) {                                                     \
        float g[NF];                                                           \
        _Pragma("unroll") for (int c = 0; c < NF; c++) {                       \
            float s = BM[c];                                                   \
            _Pragma("unroll") for (int j = 0; j < NF; j++)                     \
                s = fmaf(hv[j], WM[j * NF + c], s);                            \
            g[c] = s;                                                          \
        }                                                                      \
        uint4 a; uint2 bv;                                                     \
        a.x  = h2u(__floats2half2_rn(g[0],  g[1]));                            \
        a.y  = h2u(__floats2half2_rn(g[2],  g[3]));                            \
        a.z  = h2u(__floats2half2_rn(g[4],  g[5]));                            \
        a.w  = h2u(__floats2half2_rn(g[6],  g[7]));                            \
        bv.x = h2u(__floats2half2_rn(g[8],  g[9]));                            \
        bv.y = h2u(__floats2half2_rn(g[10], g[11]));                           \
        gA[(size_t)(BR) * 65536 + node] = a;                                   \
        gB[(size_t)(BR) * 65536 + node] = bv;                                  \
    }
    DO_G(0, Wm1, bm1)
    DO_G(1, Wm0, bm0)
    DO_G(2, Wmm1, bmm1)
#undef DO_G
}

// ---------------------------------------------------------------------------
// table: phi_br(dist)[c] = sum_j exp(-(dist-node_j)^2/(2s^2)) * Wm_br[12+j][c]
// 513 entries over [0, 0.3], f16 packed.
// ---------------------------------------------------------------------------
__global__ __launch_bounds__(256) void table_kernel(
    const float* __restrict__ Wm1, const float* __restrict__ Wm0, const float* __restrict__ Wmm1,
    uint4* __restrict__ tA, uint2* __restrict__ tB)
{
    const int br = blockIdx.x;
    const float* Wm = (br == 0) ? Wm1 : (br == 1) ? Wm0 : Wmm1;
    for (int e = threadIdx.x; e < TBL + 1; e += 256) {
        float dd = (float)e * (0.3f / (float)TBL);
        float rbf[12];
#pragma unroll
        for (int j = 0; j < 12; j++) {
            float t = dd - (0.3f / 11.0f) * (float)j;
            rbf[j] = expf(-2222.2222222222f * t * t);
        }
        float ph[NF];
#pragma unroll
        for (int c = 0; c < NF; c++) {
            float s = 0.0f;
#pragma unroll
            for (int j = 0; j < 12; j++) s = fmaf(rbf[j], Wm[(12 + j) * NF + c], s);
            ph[c] = s;
        }
        uint4 a; uint2 bv;
        a.x  = h2u(__floats2half2_rn(ph[0],  ph[1]));
        a.y  = h2u(__floats2half2_rn(ph[2],  ph[3]));
        a.z  = h2u(__floats2half2_rn(ph[4],  ph[5]));
        a.w  = h2u(__floats2half2_rn(ph[6],  ph[7]));
        bv.x = h2u(__floats2half2_rn(ph[8],  ph[9]));
        bv.y = h2u(__floats2half2_rn(ph[10], ph[11]));
        tA[br * (TBL + 1) + e] = a;
        tB[br * (TBL + 1) + e] = bv;
    }
}

// ---------------------------------------------------------------------------
// main: per (branch, batch, node-chunk). Stage g slice + table in LDS, then
// per edge: m += relu(g[idx] + lerp(table, dist)). Epilogue: sigmoid update.
// ---------------------------------------------------------------------------
__global__ __launch_bounds__(TMAIN) void main_kernel(
    const float* __restrict__ h,
    const uint4* __restrict__ gA, const uint2* __restrict__ gB,
    const uint4* __restrict__ tA, const uint2* __restrict__ tB,
    const float* __restrict__ d1, const float* __restrict__ d0, const float* __restrict__ dm1,
    const float* __restrict__ Wu1, const float* __restrict__ bu1,
    const float* __restrict__ Wu0, const float* __restrict__ bu0,
    const float* __restrict__ Wum1, const float* __restrict__ bum1,
    float* __restrict__ out)
{
    extern __shared__ char smem[];
    uint4* gAl = (uint4*)smem;
    uint2* gBl = (uint2*)(smem + 65536);
    uint4* tAl = (uint4*)(smem + 98304);
    uint2* tBl = (uint2*)(smem + 106512);

    const int q = blockIdx.x, b = blockIdx.y, br = blockIdx.z;
    const int tid = threadIdx.x;
    const size_t slice = (size_t)(br * BBAT + b) * NNODE;

    {
        const uint4* gAg = gA + slice;
        const uint2* gBg = gB + slice;
        for (int i = tid; i < NNODE; i += TMAIN) { gAl[i] = gAg[i]; gBl[i] = gBg[i]; }
        const uint4* tAg = tA + br * (TBL + 1);
        const uint2* tBg = tB + br * (TBL + 1);
        for (int i = tid; i < TBL + 1; i += TMAIN) { tAl[i] = tAg[i]; tBl[i] = tBg[i]; }
    }
    __syncthreads();

    const int n = q * NPB + tid;
    if (tid >= NPB || n >= NNODE) return;

    const float* dsel = (br == 0) ? d1 : (br == 1) ? d0 : dm1;
    const float* Wu   = (br == 0) ? Wu1 : (br == 1) ? Wu0 : Wum1;
    const float* bu   = (br == 0) ? bu1 : (br == 1) ? bu0 : bum1;

    float m[NF];
#pragma unroll
    for (int f = 0; f < NF; f++) m[f] = 0.0f;

    const float4* dp = (const float4*)(dsel + ((size_t)b * NNODE + n) * (size_t)(KNB * 2));

#define ACC(O, G, T0, T1) {                                                    \
        __half2 t0 = u2h(T0), t1 = u2h(T1);                                    \
        __half2 phi = __hfma2(f2, __hsub2(t1, t0), t0);                        \
        __half2 s2 = __hadd2(u2h(G), phi);                                     \
        float2 sf = __half22float2(s2);                                        \
        m[O]     += fmaxf(sf.x, 0.0f);                                         \
        m[O + 1] += fmaxf(sf.y, 0.0f);                                         \
    }

#pragma unroll
    for (int kt = 0; kt < 4; kt++) {
        float4 e0 = dp[kt * 4 + 0];
        float4 e1 = dp[kt * 4 + 1];
        float4 e2 = dp[kt * 4 + 2];
        float4 e3 = dp[kt * 4 + 3];
        float idxf[8] = { e0.x, e0.z, e1.x, e1.z, e2.x, e2.z, e3.x, e3.z };
        float dist[8] = { e0.y, e0.w, e1.y, e1.w, e2.y, e2.w, e3.y, e3.w };
#pragma unroll
        for (int ee = 0; ee < 8; ee++) {
            int j = (int)idxf[ee];
            uint4 ga = gAl[j];
            uint2 gb = gBl[j];
            float uu = dist[ee] * ((float)TBL / 0.3f);
            int i = (int)uu;
            i = min(i, TBL - 1);
            float fr = uu - (float)i;
            __half2 f2 = __float2half2_rn(fr);
            uint4 a0 = tAl[i];
            uint2 b0 = tBl[i];
            uint4 a1 = tAl[i + 1];
            uint2 b1 = tBl[i + 1];
            ACC(0,  ga.x, a0.x, a1.x)
            ACC(2,  ga.y, a0.y, a1.y)
            ACC(4,  ga.z, a0.z, a1.z)
            ACC(6,  ga.w, a0.w, a1.w)
            ACC(8,  gb.x, b0.x, b1.x)
            ACC(10, gb.y, b0.y, b1.y)
        }
    }
#undef ACC

    // update: out = sigmoid(h@Wu_up + m@Wu_low + bu)
    const float* hp = h + ((size_t)b * NNODE + n) * NF;
    float4 h0 = ldf4(hp), h1v = ldf4(hp + 4), h2v = ldf4(hp + 8);
    float hv[NF] = { h0.x, h0.y, h0.z, h0.w, h1v.x, h1v.y, h1v.z, h1v.w,
                     h2v.x, h2v.y, h2v.z, h2v.w };
    float ov[NF];
#pragma unroll
    for (int f = 0; f < NF; f++) {
        float a = bu[f];
#pragma unroll
        for (int j = 0; j < NF; j++) a = fmaf(hv[j], Wu[j * NF + f], a);
#pragma unroll
        for (int j = 0; j < NF; j++) a = fmaf(m[j], Wu[(NF + j) * NF + f], a);
        ov[f] = 1.0f / (1.0f + __expf(-a));
    }
    float* op = out + (slice + n) * NF;
    ((float4*)op)[0] = make_float4(ov[0], ov[1], ov[2],  ov[3]);
    ((float4*)op)[1] = make_float4(ov[4], ov[5], ov[6],  ov[7]);
    ((float4*)op)[2] = make_float4(ov[8], ov[9], ov[10], ov[11]);
}

extern "C" void kernel_launch(void* const* d_in, const int* in_sizes, int n_in,
                              void* d_out, int out_size, void* d_ws, size_t ws_size,
                              hipStream_t stream)
{
    const float* x    = (const float*)d_in[0];
    const float* d1   = (const float*)d_in[1];
    const float* d0   = (const float*)d_in[2];
    const float* dm1  = (const float*)d_in[3];
    // d_in[4] = mask, all-ones -> unused
    const float* We   = (const float*)d_in[5];
    const float* be   = (const float*)d_in[6];
    const float* Wm1  = (const float*)d_in[7];
    const float* bm1  = (const float*)d_in[8];
    const float* Wu1  = (const float*)d_in[9];
    const float* bu1  = (const float*)d_in[10];
    const float* Wm0  = (const float*)d_in[11];
    const float* bm0  = (const float*)d_in[12];
    const float* Wu0  = (const float*)d_in[13];
    const float* bu0  = (const float*)d_in[14];
    const float* Wmm1 = (const float*)d_in[15];
    const float* bmm1 = (const float*)d_in[16];
    const float* Wum1 = (const float*)d_in[17];
    const float* bum1 = (const float*)d_in[18];

    // ws layout (7.9 MB total):
    char* ws = (char*)d_ws;
    float* h  = (float*)ws;                          // 65536*12*4   = 3,145,728
    uint4* gA = (uint4*)(ws + 3145728);              // 3*65536*16   = 3,145,728
    uint2* gB = (uint2*)(ws + 6291456);              // 3*65536*8    = 1,572,864
    uint4* tA = (uint4*)(ws + 7864320);              // 3*513*16     = 24,624
    uint2* tB = (uint2*)(ws + 7888944);              // 3*513*8      = 12,312

    hipFuncSetAttribute((const void*)main_kernel,
                        hipFuncAttributeMaxDynamicSharedMemorySize, LDS_BYTES);

    prep_kernel<<<dim3(256), 256, 0, stream>>>(
        x, We, be, Wm1, bm1, Wm0, bm0, Wmm1, bmm1, h, gA, gB);
    table_kernel<<<dim3(3), 256, 0, stream>>>(Wm1, Wm0, Wmm1, tA, tB);
    main_kernel<<<dim3(5, BBAT, 3), TMAIN, LDS_BYTES, stream>>>(
        h, gA, gB, tA, tB, d1, d0, dm1,
        Wu1, bu1, Wu0, bu0, Wum1, bum1, (float*)d_out);
}